// Round 4
// baseline (557.015 us; speedup 1.0000x reference)
//
#include <hip/hip_runtime.h>

#define K_DIM 4096
#define N_DIM 4096
#define M_TOT 8192          // B * M = 2 * 4096
#define INT8_BOUND 127.0f
#define BK 128              // k-bytes per GEMM k-tile
#define NT (K_DIM / BK)     // 32 k-tiles

typedef int v4i  __attribute__((ext_vector_type(4)));
typedef int v16i __attribute__((ext_vector_type(16)));

// async global->LDS, 16B per lane; dest = wave-uniform base + lane*16
#define GLOAD_LDS16(g, l)                                                      \
    __builtin_amdgcn_global_load_lds(                                          \
        (const __attribute__((address_space(1))) void*)(g),                    \
        (__attribute__((address_space(3))) void*)(l), 16, 0, 0)

__device__ __forceinline__ int sat8(float x) {
    return (int)fminf(127.f, fmaxf(-127.f, x));
}

// ---------------------------------------------------------------------------
// Kernel 1: quantize lhs rows. One block (256 thr) per row of K=4096 floats.
// ---------------------------------------------------------------------------
__global__ __launch_bounds__(256) void quant_lhs_kernel(const float* __restrict__ lhs,
                                                        char* __restrict__ q_l,
                                                        float* __restrict__ s_l) {
    __shared__ float red[4];
    const int row = blockIdx.x;
    const int t = threadIdx.x;
    const float4* x4 = (const float4*)(lhs + (size_t)row * K_DIM);

    float4 v[4];
    float amax = 0.f;
#pragma unroll
    for (int c = 0; c < 4; ++c) {
        v[c] = x4[t + c * 256];
        amax = fmaxf(amax, fmaxf(fmaxf(fabsf(v[c].x), fabsf(v[c].y)),
                                 fmaxf(fabsf(v[c].z), fabsf(v[c].w))));
    }
#pragma unroll
    for (int off = 32; off > 0; off >>= 1)
        amax = fmaxf(amax, __shfl_xor(amax, off, 64));
    if ((t & 63) == 0) red[t >> 6] = amax;
    __syncthreads();
    amax = fmaxf(fmaxf(red[0], red[1]), fmaxf(red[2], red[3]));

    const float scale = (amax > 0.f) ? (amax / INT8_BOUND) : 1.0f;
    const float inv = (amax > 0.f) ? (INT8_BOUND / amax) : 1.0f;
    if (t == 0) s_l[row] = scale;

    int* qrow = (int*)(q_l + (size_t)row * K_DIM);
#pragma unroll
    for (int c = 0; c < 4; ++c) {
        int b0 = sat8(rintf(v[c].x * inv));
        int b1 = sat8(rintf(v[c].y * inv));
        int b2 = sat8(rintf(v[c].z * inv));
        int b3 = sat8(rintf(v[c].w * inv));
        qrow[t + c * 256] = (b0 & 0xff) | ((b1 & 0xff) << 8) | ((b2 & 0xff) << 16) | (b3 << 24);
    }
}

// ---------------------------------------------------------------------------
// Kernel 2: per-column absmax of rhs [K x N].
// ---------------------------------------------------------------------------
__global__ __launch_bounds__(256) void rhs_amax_kernel(const float* __restrict__ rhs,
                                                       unsigned* __restrict__ amax_r) {
    const int t = threadIdx.x;
    const int nf = blockIdx.x * 256 + t;       // float4 column group 0..1023
    const int k0 = blockIdx.y * 64;
    const float4* r4 = (const float4*)rhs;
    float4 m = {0.f, 0.f, 0.f, 0.f};
#pragma unroll 8
    for (int k = 0; k < 64; ++k) {
        float4 v = r4[(size_t)(k0 + k) * (N_DIM / 4) + nf];
        m.x = fmaxf(m.x, fabsf(v.x));
        m.y = fmaxf(m.y, fabsf(v.y));
        m.z = fmaxf(m.z, fabsf(v.z));
        m.w = fmaxf(m.w, fabsf(v.w));
    }
    atomicMax(&amax_r[nf * 4 + 0], __float_as_uint(m.x));
    atomicMax(&amax_r[nf * 4 + 1], __float_as_uint(m.y));
    atomicMax(&amax_r[nf * 4 + 2], __float_as_uint(m.z));
    atomicMax(&amax_r[nf * 4 + 3], __float_as_uint(m.w));
}

// ---------------------------------------------------------------------------
// Kernel 3: quantize rhs and transpose to q_rT (int8, [N x K], K contiguous).
// ---------------------------------------------------------------------------
__global__ __launch_bounds__(256) void rhs_quant_kernel(const float* __restrict__ rhs,
                                                        const unsigned* __restrict__ amax_r,
                                                        char* __restrict__ q_rt) {
    __shared__ char tile[64 * 136];   // [n][k], stride 136
    const int t = threadIdx.x;
    const int k0 = blockIdx.x * 128;
    const int n0 = blockIdx.y * 64;
    const int nf = t & 15;            // float4 column group
    const int kb = (t >> 4) * 8;      // contiguous 8-k strip

    float inv[4];
#pragma unroll
    for (int q = 0; q < 4; ++q) {
        float am = __uint_as_float(amax_r[n0 + nf * 4 + q]);
        inv[q] = (am > 0.f) ? (INT8_BOUND / am) : 1.f;
    }
    const float4* r4 = (const float4*)rhs;
    int vals[4][8];
#pragma unroll
    for (int c = 0; c < 8; ++c) {
        float4 v = r4[(size_t)(k0 + kb + c) * (N_DIM / 4) + (n0 >> 2) + nf];
        vals[0][c] = sat8(rintf(v.x * inv[0]));
        vals[1][c] = sat8(rintf(v.y * inv[1]));
        vals[2][c] = sat8(rintf(v.z * inv[2]));
        vals[3][c] = sat8(rintf(v.w * inv[3]));
    }
#pragma unroll
    for (int q = 0; q < 4; ++q) {
        int2 p;
        p.x = (vals[q][0] & 0xff) | ((vals[q][1] & 0xff) << 8) |
              ((vals[q][2] & 0xff) << 16) | (vals[q][3] << 24);
        p.y = (vals[q][4] & 0xff) | ((vals[q][5] & 0xff) << 8) |
              ((vals[q][6] & 0xff) << 16) | (vals[q][7] << 24);
        *(int2*)&tile[(nf * 4 + q) * 136 + kb] = p;
    }
    __syncthreads();
#pragma unroll
    for (int c = 0; c < 2; ++c) {
        const int idx = c * 256 + t;
        const int row = idx >> 3;          // 0..63
        const int ch = (idx & 7) * 16;     // 0..112
        *(v4i*)&q_rt[(size_t)(n0 + row) * K_DIM + k0 + ch] = *(const v4i*)&tile[row * 136 + ch];
    }
}

// ---------------------------------------------------------------------------
// Kernel 4: int8 MFMA GEMM, 256x256 tile, BK=128, 8 waves (512 thr),
// per-wave 128x64 = acc[4][2].  A DIRECT global->VGPR, B via LDS dbuf.
//
// WHY (R3 post-mortem): with both operands in LDS, you cannot have BOTH
// >=2 waves/SIMD (needs <=256 VGPR -> acc<=4x2 -> reads/MFMA 0.75 ->
// LDS-oversubscribed ~R2) AND LDS-light (needs acc 4x4 -> 1 wave/SIMD ->
// phase bubbles exposed ~R3). Both walls measured 156us at 39% MfmaUtil.
// Fix: A-fragments load straight from L2 (A-strip = 4MB/XCD, L2-resident
// by the serpentine swizzle; 4 wn-sibling waves share each 128B line -> L1).
// LDS holds only B: 32KB stage + 64KB reads per tile per CU (~1280cy)
// << MFMA (2341cy). Registers: 128 acc + 64 A + 32 B + addr ~= 250 -> 2
// waves/SIMD hide the remaining bubbles.
//
// Schedule per k-tile: ONE __syncthreads() (its vmcnt(0)+lgkmcnt(0) is the
// dbuf fence). All operand waits are compiler-inserted (normal loads).
//   issue 16 A-loads(t) -> issue 4 gload_lds B-stage(t+1)->dn ->
//   8 ds_read bf(t,d) -> 32 MFMA -> __syncthreads().
// dn-overwrite safety: dn's readers (tile t-1) drained by t-1's barrier.
// dn-read safety: stage(t+1) landed at t's vmcnt(0)+barrier.
// ---------------------------------------------------------------------------
#define STAGE_B(dd, kt)                                                        \
    {                                                                          \
        const char* gb = baseB + (kt) * BK;                                    \
        char* lb = &lds[(dd) * 32768];                                         \
        _Pragma("unroll")                                                      \
        for (int g = 0; g < 4; ++g) GLOAD_LDS16(gb + goff[g], lb + loff[g]);   \
    }

__global__ __launch_bounds__(512, 2) void gemm_i8_kernel(const char* __restrict__ qa,
                                                         const char* __restrict__ qb,
                                                         const float* __restrict__ s_l,
                                                         const unsigned* __restrict__ amax_r,
                                                         float* __restrict__ out) {
    __shared__ char lds[65536];       // B double buffer: 2 x (256 rows x 128 B)
    const int t = threadIdx.x;
    const int lane = t & 63;
    const int ln31 = lane & 31;
    const int lhi = lane >> 5;
    const int wave = t >> 6;          // 0..7
    const int wm = wave >> 2;         // 0..1 (M half: 128 rows)
    const int wn = wave & 3;          // 0..3 (N quarter: 64 cols)

    // XCD serpentine: XCD x owns bx strip [4x,4x+4) over all by (A-strip 4MB,
    // L2-resident); by-major serpentine for B-panel sharing in time.
    const int orig = blockIdx.x;
    const int x = orig & 7;
    const int idx = orig >> 3;         // 0..63
    const int by = idx >> 2;           // 0..15
    const int bxo = (by & 1) ? (3 - (idx & 3)) : (idx & 3);
    const int bx = x * 4 + bxo;        // 0..31
    const size_t rowA0 = (size_t)bx * 256;
    const size_t rowB0 = (size_t)by * 256;

    v16i acc[4][2];
#pragma unroll
    for (int i = 0; i < 4; ++i)
#pragma unroll
        for (int j = 0; j < 2; ++j) acc[i][j] = (v16i)(0);

    // B staging: slot s = g*512+t; r = s>>3 (row 0..255), cs = s&7 (16B chunk
    // in 128B row), src chunk cg = cs ^ (r&7): linear LDS dest + pre-swizzled
    // global source (rule #21).
    int goff[4], loff[4];
#pragma unroll
    for (int g = 0; g < 4; ++g) {
        const int s = g * 512 + t;
        const int r = s >> 3;
        const int cg = (s & 7) ^ (r & 7);
        goff[g] = r * K_DIM + cg * 16;
        loff[g] = s * 16;
    }
    const char* baseB = qb + rowB0 * K_DIM;

    // A direct pointers: one per i-subtile; k offset kt*128 + ks*32 (<=4064,
    // fits the 13-bit signed global_load immediate after a per-tile add).
    const char* aptr[4];
#pragma unroll
    for (int i = 0; i < 4; ++i)
        aptr[i] = qa + (rowA0 + (size_t)(wm * 128 + i * 32 + ln31)) * K_DIM + lhi * 16;

    // B read offsets: row n = wn*64 + j*32 + ln31; chunk c = 2*ks + lhi,
    // lds chunk = c ^ (row&7), row&7 == ln31&7.
    int boff[2], cw[4];
#pragma unroll
    for (int j = 0; j < 2; ++j) boff[j] = (wn * 64 + j * 32 + ln31) * BK;
#pragma unroll
    for (int ks = 0; ks < 4; ++ks) cw[ks] = (((2 * ks + lhi) ^ (ln31 & 7)) << 4);

    // Prologue: stage B tile 0 into buf0.
    STAGE_B(0, 0);
    __syncthreads();

    for (int kt = 0; kt < NT; ++kt) {
        const int d = kt & 1;

        // 16 A-loads for this tile (needed soonest -> issued first).
        v4i ar[4][4];
#pragma unroll
        for (int ks = 0; ks < 4; ++ks)
#pragma unroll
            for (int i = 0; i < 4; ++i)
                ar[i][ks] = *(const v4i*)(aptr[i] + kt * BK + ks * 32);

        // Prefetch next B tile into the other buffer (landed by syncthreads).
        if (kt + 1 < NT) STAGE_B(d ^ 1, kt + 1);

        // 8 B-fragment reads from LDS.
        v4i bf[2][4];
        const char* pb = &lds[d * 32768];
#pragma unroll
        for (int ks = 0; ks < 4; ++ks)
#pragma unroll
            for (int j = 0; j < 2; ++j)
                bf[j][ks] = *(const v4i*)(pb + boff[j] + cw[ks]);

        // 32 MFMAs; compiler inserts vmcnt/lgkmcnt before first uses.
#pragma unroll
        for (int ks = 0; ks < 4; ++ks)
#pragma unroll
            for (int i = 0; i < 4; ++i)
#pragma unroll
                for (int j = 0; j < 2; ++j)
                    acc[i][j] = __builtin_amdgcn_mfma_i32_32x32x32_i8(
                        ar[i][ks], bf[j][ks], acc[i][j], 0, 0, 0);

        // vmcnt(0)+lgkmcnt(0)+barrier: B dbuf fence (and drains A leftovers).
        __syncthreads();
    }

    // Epilogue. 32x32 C/D layout: col=lane&31, row=(reg&3)+8*(reg>>2)+4*(lane>>5)
    float sr[2];
#pragma unroll
    for (int j = 0; j < 2; ++j) {
        const float am = __uint_as_float(amax_r[(int)rowB0 + wn * 64 + j * 32 + ln31]);
        sr[j] = (am > 0.f) ? (am / INT8_BOUND) : 1.f;
    }
#pragma unroll
    for (int i = 0; i < 4; ++i) {
        const int rbase = (int)rowA0 + wm * 128 + i * 32 + 4 * lhi;
#pragma unroll
        for (int j = 0; j < 2; ++j) {
            const int col = (int)rowB0 + wn * 64 + j * 32 + ln31;
            const v16i a = acc[i][j];
#pragma unroll
            for (int reg = 0; reg < 16; ++reg) {
                const int row = rbase + (reg & 3) + 8 * (reg >> 2);
                out[(size_t)row * N_DIM + col] = (float)a[reg] * s_l[row] * sr[j];
            }
        }
    }
}

// ---------------------------------------------------------------------------
extern "C" void kernel_launch(void* const* d_in, const int* in_sizes, int n_in,
                              void* d_out, int out_size, void* d_ws, size_t ws_size,
                              hipStream_t stream) {
    const float* lhs = (const float*)d_in[0];   // [2,4096,4096] fp32
    const float* rhs = (const float*)d_in[1];   // [4096,4096]  fp32
    float* out = (float*)d_out;                 // [2,4096,4096] fp32

    char* ws = (char*)d_ws;
    char* q_l = ws;                                        // 32 MB
    char* q_rt = ws + (size_t)M_TOT * K_DIM;               // 16 MB
    float* s_l = (float*)(q_rt + (size_t)N_DIM * K_DIM);   // 32 KB
    unsigned* amax_r = (unsigned*)(s_l + M_TOT);           // 16 KB

    hipMemsetAsync(amax_r, 0, N_DIM * sizeof(unsigned), stream);

    quant_lhs_kernel<<<M_TOT, 256, 0, stream>>>(lhs, q_l, s_l);
    rhs_amax_kernel<<<dim3(N_DIM / 1024, K_DIM / 64), 256, 0, stream>>>(rhs, amax_r);
    rhs_quant_kernel<<<dim3(K_DIM / 128, N_DIM / 64), 256, 0, stream>>>(rhs, amax_r, q_rt);
    gemm_i8_kernel<<<dim3((M_TOT / 256) * (N_DIM / 256)), 512, 0, stream>>>(q_l, q_rt, s_l, amax_r, out);
}

// Round 5
// 509.702 us; speedup vs baseline: 1.0928x; 1.0928x over previous
//
#include <hip/hip_runtime.h>

#define K_DIM 4096
#define N_DIM 4096
#define M_TOT 8192          // B * M = 2 * 4096
#define INT8_BOUND 127.0f
#define BK 128              // k-bytes per GEMM k-tile
#define NT (K_DIM / BK)     // 32 k-tiles

typedef int v4i  __attribute__((ext_vector_type(4)));
typedef int v16i __attribute__((ext_vector_type(16)));

// async global->LDS, 16B per lane; dest = wave-uniform base + lane*16
#define GLOAD_LDS16(g, l)                                                      \
    __builtin_amdgcn_global_load_lds(                                          \
        (const __attribute__((address_space(1))) void*)(g),                    \
        (__attribute__((address_space(3))) void*)(l), 16, 0, 0)

__device__ __forceinline__ int sat8(float x) {
    return (int)fminf(127.f, fmaxf(-127.f, x));
}

// ---------------------------------------------------------------------------
// Kernel 1: quantize lhs AND pack into MFMA-fragment order.
// Output q_lp[m32][k32][lane][16B]: for fragment (m32,k32), lane l holds
// A[row = m32*32 + (l&31)][k = k32*32 + 16*(l>>5) .. +16).  (Mapping proven
// by the previous LDS-based GEMMs: af read row=ln31, 16B-chunk=lhi.)
// One block per 32-row group; 8 threads per row; 2 passes (amax, then pack).
// ---------------------------------------------------------------------------
__global__ __launch_bounds__(256) void quant_lhs_kernel(const float* __restrict__ lhs,
                                                        char* __restrict__ q_lp,
                                                        float* __restrict__ s_l) {
    const int t = threadIdx.x;
    const int r = t >> 3;              // row within group 0..31
    const int sub = t & 7;             // 8 threads per row
    const int m32 = blockIdx.x;        // 0..255
    const int row = m32 * 32 + r;
    const float4* x4 = (const float4*)(lhs + (size_t)row * K_DIM);

    // pass 1: row absmax (8 threads stride over 1024 float4s)
    float am = 0.f;
#pragma unroll 8
    for (int c = 0; c < 128; ++c) {
        float4 v = x4[sub + 8 * c];
        am = fmaxf(am, fmaxf(fmaxf(fabsf(v.x), fabsf(v.y)),
                             fmaxf(fabsf(v.z), fabsf(v.w))));
    }
#pragma unroll
    for (int off = 1; off <= 4; off <<= 1)
        am = fmaxf(am, __shfl_xor(am, off, 64));   // 8 row-threads are adjacent lanes

    const float scale = (am > 0.f) ? (am / INT8_BOUND) : 1.f;
    const float inv = (am > 0.f) ? (INT8_BOUND / am) : 1.f;
    if (sub == 0) s_l[row] = scale;

    // pass 2 (L2-hot reread): each thread owns 16-byte k-chunks c16 = sub+8cc,
    // quantizes 16 floats -> one v4i store into the packed fragment.
    char* gbase = q_lp + (size_t)m32 * 131072;     // 128 frags * 1024 B
#pragma unroll 2
    for (int cc = 0; cc < 32; ++cc) {
        const int c16 = sub + 8 * cc;              // 0..255
        float4 a[4];
#pragma unroll
        for (int j = 0; j < 4; ++j) a[j] = x4[4 * c16 + j];
        int w[4];
#pragma unroll
        for (int j = 0; j < 4; ++j) {
            const int b0 = sat8(rintf(a[j].x * inv));
            const int b1 = sat8(rintf(a[j].y * inv));
            const int b2 = sat8(rintf(a[j].z * inv));
            const int b3 = sat8(rintf(a[j].w * inv));
            w[j] = (b0 & 0xff) | ((b1 & 0xff) << 8) | ((b2 & 0xff) << 16) | (b3 << 24);
        }
        v4i p = {w[0], w[1], w[2], w[3]};
        // frag k32 = c16>>1; lane slot = (c16&1)*32 + r
        *(v4i*)(gbase + (c16 >> 1) * 1024 + (((c16 & 1) << 5) + r) * 16) = p;
    }
}

// ---------------------------------------------------------------------------
// Kernel 2: per-column absmax of rhs [K x N].
// ---------------------------------------------------------------------------
__global__ __launch_bounds__(256) void rhs_amax_kernel(const float* __restrict__ rhs,
                                                       unsigned* __restrict__ amax_r) {
    const int t = threadIdx.x;
    const int nf = blockIdx.x * 256 + t;       // float4 column group 0..1023
    const int k0 = blockIdx.y * 64;
    const float4* r4 = (const float4*)rhs;
    float4 m = {0.f, 0.f, 0.f, 0.f};
#pragma unroll 8
    for (int k = 0; k < 64; ++k) {
        float4 v = r4[(size_t)(k0 + k) * (N_DIM / 4) + nf];
        m.x = fmaxf(m.x, fabsf(v.x));
        m.y = fmaxf(m.y, fabsf(v.y));
        m.z = fmaxf(m.z, fabsf(v.z));
        m.w = fmaxf(m.w, fabsf(v.w));
    }
    atomicMax(&amax_r[nf * 4 + 0], __float_as_uint(m.x));
    atomicMax(&amax_r[nf * 4 + 1], __float_as_uint(m.y));
    atomicMax(&amax_r[nf * 4 + 2], __float_as_uint(m.z));
    atomicMax(&amax_r[nf * 4 + 3], __float_as_uint(m.w));
}

// ---------------------------------------------------------------------------
// Kernel 3: quantize rhs and transpose to q_rT (int8, [N x K], K contiguous).
// ---------------------------------------------------------------------------
__global__ __launch_bounds__(256) void rhs_quant_kernel(const float* __restrict__ rhs,
                                                        const unsigned* __restrict__ amax_r,
                                                        char* __restrict__ q_rt) {
    __shared__ char tile[64 * 136];   // [n][k], stride 136
    const int t = threadIdx.x;
    const int k0 = blockIdx.x * 128;
    const int n0 = blockIdx.y * 64;
    const int nf = t & 15;            // float4 column group
    const int kb = (t >> 4) * 8;      // contiguous 8-k strip

    float inv[4];
#pragma unroll
    for (int q = 0; q < 4; ++q) {
        float am = __uint_as_float(amax_r[n0 + nf * 4 + q]);
        inv[q] = (am > 0.f) ? (INT8_BOUND / am) : 1.f;
    }
    const float4* r4 = (const float4*)rhs;
    int vals[4][8];
#pragma unroll
    for (int c = 0; c < 8; ++c) {
        float4 v = r4[(size_t)(k0 + kb + c) * (N_DIM / 4) + (n0 >> 2) + nf];
        vals[0][c] = sat8(rintf(v.x * inv[0]));
        vals[1][c] = sat8(rintf(v.y * inv[1]));
        vals[2][c] = sat8(rintf(v.z * inv[2]));
        vals[3][c] = sat8(rintf(v.w * inv[3]));
    }
#pragma unroll
    for (int q = 0; q < 4; ++q) {
        int2 p;
        p.x = (vals[q][0] & 0xff) | ((vals[q][1] & 0xff) << 8) |
              ((vals[q][2] & 0xff) << 16) | (vals[q][3] << 24);
        p.y = (vals[q][4] & 0xff) | ((vals[q][5] & 0xff) << 8) |
              ((vals[q][6] & 0xff) << 16) | (vals[q][7] << 24);
        *(int2*)&tile[(nf * 4 + q) * 136 + kb] = p;
    }
    __syncthreads();
#pragma unroll
    for (int c = 0; c < 2; ++c) {
        const int idx = c * 256 + t;
        const int row = idx >> 3;          // 0..63
        const int ch = (idx & 7) * 16;     // 0..112
        *(v4i*)&q_rt[(size_t)(n0 + row) * K_DIM + k0 + ch] = *(const v4i*)&tile[row * 136 + ch];
    }
}

// ---------------------------------------------------------------------------
// Kernel 4: int8 MFMA GEMM, 256x256 tile, BK=128, 8 waves, acc[4][2].
// A: DIRECT global->VGPR from fragment-packed q_lp (each fragment = wave-
// contiguous 1024 B -> perfectly coalesced; L1-resident, shared by the 4
// wn-sibling waves).  B: LDS dbuf 2x32KB (R4's proven path).
//
// WHY (R0-R4 accounting): per CU, one ds_read_b128 (9.1 cy @112 B/cy) costs
// the same as one mfma_i32_32x32x32_i8 (9.1 cy @7168 ops/cy), so LDS-read
// time = MFMA time * (m+n)/(m*n); with W*m*n=64 forced and 256-VGPR capping
// m*n<=8 for 2 waves/SIMD, every all-LDS geometry has ratio >=0.75 -> the
// 156us/39% wall (R0/R2/R3). R4 proved A-from-global fixes the ratio but
// died on uncoalesced access (32 lines/load). Fragment packing fixes that.
// B-only LDS: 64KB read + 32KB stage per tile per CU ~= 1150 cy << 2341 cy
// MFMA.  A loads issued BEFORE the B-stage so the compiler's mid-tile
// vmcnt wait for A retires only A, keeping the prefetch in flight.
// ---------------------------------------------------------------------------
#define STAGE_B(dd, kt)                                                        \
    {                                                                          \
        const char* gb = baseB + (kt) * BK;                                    \
        char* lb = &lds[(dd) * 32768];                                         \
        _Pragma("unroll")                                                      \
        for (int g = 0; g < 4; ++g) GLOAD_LDS16(gb + goff[g], lb + loff[g]);   \
    }

__global__ __launch_bounds__(512, 2) void gemm_i8_kernel(const char* __restrict__ qap,
                                                         const char* __restrict__ qb,
                                                         const float* __restrict__ s_l,
                                                         const unsigned* __restrict__ amax_r,
                                                         float* __restrict__ out) {
    __shared__ char lds[65536];       // B double buffer: 2 x (256 rows x 128 B)
    const int t = threadIdx.x;
    const int lane = t & 63;
    const int ln31 = lane & 31;
    const int lhi = lane >> 5;
    const int wave = t >> 6;          // 0..7
    const int wm = wave >> 2;         // 0..1 (M half: 128 rows)
    const int wn = wave & 3;          // 0..3 (N quarter: 64 cols)

    // XCD serpentine: XCD x owns bx strip [4x,4x+4) over all by (A-strip 4MB,
    // L2-resident); by-major serpentine for B-panel sharing in time.
    const int orig = blockIdx.x;
    const int x = orig & 7;
    const int idx = orig >> 3;         // 0..63
    const int by = idx >> 2;           // 0..15
    const int bxo = (by & 1) ? (3 - (idx & 3)) : (idx & 3);
    const int bx = x * 4 + bxo;        // 0..31
    const size_t rowB0 = (size_t)by * 256;

    v16i acc[4][2];
#pragma unroll
    for (int i = 0; i < 4; ++i)
#pragma unroll
        for (int j = 0; j < 2; ++j) acc[i][j] = (v16i)(0);

    // B staging: slot s = g*512+t; r = s>>3 (row), cs = s&7 (16B chunk in
    // 128B row), src chunk cg = cs ^ (r&7): linear LDS dest + pre-swizzled
    // global source (rule #21).
    int goff[4], loff[4];
#pragma unroll
    for (int g = 0; g < 4; ++g) {
        const int s = g * 512 + t;
        const int r = s >> 3;
        const int cg = (s & 7) ^ (r & 7);
        goff[g] = r * K_DIM + cg * 16;
        loff[g] = s * 16;
    }
    const char* baseB = qb + rowB0 * K_DIM;

    // A packed base: wave's fragments are m32 = bx*8 + wm*4 + i, k32 = kt*4+ks.
    const char* abase = qap + (size_t)(bx * 8 + wm * 4) * 131072 + lane * 16;

    // B read offsets: row n = wn*64 + j*32 + ln31; chunk c = 2*ks + lhi,
    // lds chunk = c ^ (row&7), row&7 == ln31&7.
    int boff[2], cw[4];
#pragma unroll
    for (int j = 0; j < 2; ++j) boff[j] = (wn * 64 + j * 32 + ln31) * BK;
#pragma unroll
    for (int ks = 0; ks < 4; ++ks) cw[ks] = (((2 * ks + lhi) ^ (ln31 & 7)) << 4);

    // Prologue: stage B tile 0 into buf0.
    STAGE_B(0, 0);
    __syncthreads();

    for (int kt = 0; kt < NT; ++kt) {
        const int d = kt & 1;

        // 16 A-fragment loads (wave-contiguous 1024 B each), issued FIRST so
        // they are older than the B-stage in the vmcnt FIFO.
        v4i ar[4][4];
#pragma unroll
        for (int ks = 0; ks < 4; ++ks)
#pragma unroll
            for (int i = 0; i < 4; ++i)
                ar[i][ks] = *(const v4i*)(abase + (size_t)i * 131072 + (kt * 4 + ks) * 1024);

        // Prefetch next B tile into the other buffer (landed by syncthreads).
        if (kt + 1 < NT) STAGE_B(d ^ 1, kt + 1);

        // 8 B-fragment reads from LDS.
        v4i bf[2][4];
        const char* pb = &lds[d * 32768];
#pragma unroll
        for (int ks = 0; ks < 4; ++ks)
#pragma unroll
            for (int j = 0; j < 2; ++j)
                bf[j][ks] = *(const v4i*)(pb + boff[j] + cw[ks]);

        // 32 MFMAs; compiler inserts fine-grained vmcnt/lgkmcnt before uses.
#pragma unroll
        for (int ks = 0; ks < 4; ++ks)
#pragma unroll
            for (int i = 0; i < 4; ++i)
#pragma unroll
                for (int j = 0; j < 2; ++j)
                    acc[i][j] = __builtin_amdgcn_mfma_i32_32x32x32_i8(
                        ar[i][ks], bf[j][ks], acc[i][j], 0, 0, 0);

        // vmcnt(0)+lgkmcnt(0)+barrier: B dbuf fence.
        __syncthreads();
    }

    // Epilogue. 32x32 C/D layout: col=lane&31, row=(reg&3)+8*(reg>>2)+4*(lane>>5)
    const size_t rowA0 = (size_t)bx * 256;
    float sr[2];
#pragma unroll
    for (int j = 0; j < 2; ++j) {
        const float am = __uint_as_float(amax_r[(int)rowB0 + wn * 64 + j * 32 + ln31]);
        sr[j] = (am > 0.f) ? (am / INT8_BOUND) : 1.f;
    }
#pragma unroll
    for (int i = 0; i < 4; ++i) {
        const int rbase = (int)rowA0 + wm * 128 + i * 32 + 4 * lhi;
#pragma unroll
        for (int j = 0; j < 2; ++j) {
            const int col = (int)rowB0 + wn * 64 + j * 32 + ln31;
            const v16i a = acc[i][j];
#pragma unroll
            for (int reg = 0; reg < 16; ++reg) {
                const int row = rbase + (reg & 3) + 8 * (reg >> 2);
                out[(size_t)row * N_DIM + col] = (float)a[reg] * s_l[row] * sr[j];
            }
        }
    }
}

// ---------------------------------------------------------------------------
extern "C" void kernel_launch(void* const* d_in, const int* in_sizes, int n_in,
                              void* d_out, int out_size, void* d_ws, size_t ws_size,
                              hipStream_t stream) {
    const float* lhs = (const float*)d_in[0];   // [2,4096,4096] fp32
    const float* rhs = (const float*)d_in[1];   // [4096,4096]  fp32
    float* out = (float*)d_out;                 // [2,4096,4096] fp32

    char* ws = (char*)d_ws;
    char* q_lp = ws;                                       // 32 MB (packed A)
    char* q_rt = ws + (size_t)M_TOT * K_DIM;               // 16 MB
    float* s_l = (float*)(q_rt + (size_t)N_DIM * K_DIM);   // 32 KB
    unsigned* amax_r = (unsigned*)(s_l + M_TOT);           // 16 KB

    hipMemsetAsync(amax_r, 0, N_DIM * sizeof(unsigned), stream);

    quant_lhs_kernel<<<M_TOT / 32, 256, 0, stream>>>(lhs, q_lp, s_l);
    rhs_amax_kernel<<<dim3(N_DIM / 1024, K_DIM / 64), 256, 0, stream>>>(rhs, amax_r);
    rhs_quant_kernel<<<dim3(K_DIM / 128, N_DIM / 64), 256, 0, stream>>>(rhs, amax_r, q_rt);
    gemm_i8_kernel<<<dim3((M_TOT / 256) * (N_DIM / 256)), 512, 0, stream>>>(q_lp, q_rt, s_l, amax_r, out);
}

// Round 7
// 414.230 us; speedup vs baseline: 1.3447x; 1.2305x over previous
//
#include <hip/hip_runtime.h>

#define K_DIM 4096
#define N_DIM 4096
#define M_TOT 8192          // B * M = 2 * 4096
#define INT8_BOUND 127.0f
#define BK 128              // k-bytes per GEMM k-tile
#define NT (K_DIM / BK)     // 32 k-tiles

typedef int v4i  __attribute__((ext_vector_type(4)));
typedef int v16i __attribute__((ext_vector_type(16)));

// async global->LDS, 16B per lane; dest = wave-uniform base + lane*16
#define GLOAD_LDS16(g, l)                                                      \
    __builtin_amdgcn_global_load_lds(                                          \
        (const __attribute__((address_space(1))) void*)(g),                    \
        (__attribute__((address_space(3))) void*)(l), 16, 0, 0)

__device__ __forceinline__ int sat8(float x) {
    return (int)fminf(127.f, fmaxf(-127.f, x));
}

// ---------------------------------------------------------------------------
// Kernel 1 (FUSED): blocks [0, 8192): quantize one lhs row each (single HBM
// pass, values held in registers — R0's proven kernel).  Blocks [8192, 9216):
// rhs per-column absmax, 16 k-rows per block (4x the parallelism of the old
// 64-row version; 16 outstanding loads).  Fusing removes a dispatch AND lets
// the two independent passes overlap instead of serializing on the stream.
// NOTE: the __syncthreads below is inside a BLOCK-UNIFORM branch (bid) — legal.
// ---------------------------------------------------------------------------
__global__ __launch_bounds__(256) void prep_kernel(const float* __restrict__ lhs,
                                                   const float* __restrict__ rhs,
                                                   char* __restrict__ q_l,
                                                   float* __restrict__ s_l,
                                                   unsigned* __restrict__ amax_r) {
    const int t = threadIdx.x;
    const int bid = blockIdx.x;

    if (bid < M_TOT) {
        // ---- lhs row quantize (one block per row of K=4096 floats) ----
        __shared__ float red[4];
        const int row = bid;
        const float4* x4 = (const float4*)(lhs + (size_t)row * K_DIM);

        float4 v[4];
        float amax = 0.f;
#pragma unroll
        for (int c = 0; c < 4; ++c) {
            v[c] = x4[t + c * 256];
            amax = fmaxf(amax, fmaxf(fmaxf(fabsf(v[c].x), fabsf(v[c].y)),
                                     fmaxf(fabsf(v[c].z), fabsf(v[c].w))));
        }
#pragma unroll
        for (int off = 32; off > 0; off >>= 1)
            amax = fmaxf(amax, __shfl_xor(amax, off, 64));
        if ((t & 63) == 0) red[t >> 6] = amax;
        __syncthreads();
        amax = fmaxf(fmaxf(red[0], red[1]), fmaxf(red[2], red[3]));

        const float scale = (amax > 0.f) ? (amax / INT8_BOUND) : 1.0f;
        const float inv = (amax > 0.f) ? (INT8_BOUND / amax) : 1.0f;
        if (t == 0) s_l[row] = scale;

        int* qrow = (int*)(q_l + (size_t)row * K_DIM);
#pragma unroll
        for (int c = 0; c < 4; ++c) {
            int b0 = sat8(rintf(v[c].x * inv));
            int b1 = sat8(rintf(v[c].y * inv));
            int b2 = sat8(rintf(v[c].z * inv));
            int b3 = sat8(rintf(v[c].w * inv));
            qrow[t + c * 256] = (b0 & 0xff) | ((b1 & 0xff) << 8) |
                                ((b2 & 0xff) << 16) | (b3 << 24);
        }
    } else {
        // ---- rhs per-column absmax: 16 k-rows per block ----
        const int r = bid - M_TOT;         // 0..1023
        const int nf = (r & 3) * 256 + t;  // float4 column group 0..1023
        const int k0 = (r >> 2) * 16;      // k-row start, 256 groups of 16
        const float4* r4 = (const float4*)rhs;
        float4 m = {0.f, 0.f, 0.f, 0.f};
#pragma unroll
        for (int k = 0; k < 16; ++k) {
            float4 v = r4[(size_t)(k0 + k) * (N_DIM / 4) + nf];
            m.x = fmaxf(m.x, fabsf(v.x));
            m.y = fmaxf(m.y, fabsf(v.y));
            m.z = fmaxf(m.z, fabsf(v.z));
            m.w = fmaxf(m.w, fabsf(v.w));
        }
        atomicMax(&amax_r[nf * 4 + 0], __float_as_uint(m.x));
        atomicMax(&amax_r[nf * 4 + 1], __float_as_uint(m.y));
        atomicMax(&amax_r[nf * 4 + 2], __float_as_uint(m.z));
        atomicMax(&amax_r[nf * 4 + 3], __float_as_uint(m.w));
    }
}

// ---------------------------------------------------------------------------
// Kernel 3: quantize rhs and transpose to q_rT (int8, [N x K], K contiguous).
// (rhs is L3-resident from the amax pass -> fast reread.)
// ---------------------------------------------------------------------------
__global__ __launch_bounds__(256) void rhs_quant_kernel(const float* __restrict__ rhs,
                                                        const unsigned* __restrict__ amax_r,
                                                        char* __restrict__ q_rt) {
    __shared__ char tile[64 * 136];   // [n][k], stride 136
    const int t = threadIdx.x;
    const int k0 = blockIdx.x * 128;
    const int n0 = blockIdx.y * 64;
    const int nf = t & 15;            // float4 column group
    const int kb = (t >> 4) * 8;      // contiguous 8-k strip

    float inv[4];
#pragma unroll
    for (int q = 0; q < 4; ++q) {
        float am = __uint_as_float(amax_r[n0 + nf * 4 + q]);
        inv[q] = (am > 0.f) ? (INT8_BOUND / am) : 1.f;
    }
    const float4* r4 = (const float4*)rhs;
    int vals[4][8];
#pragma unroll
    for (int c = 0; c < 8; ++c) {
        float4 v = r4[(size_t)(k0 + kb + c) * (N_DIM / 4) + (n0 >> 2) + nf];
        vals[0][c] = sat8(rintf(v.x * inv[0]));
        vals[1][c] = sat8(rintf(v.y * inv[1]));
        vals[2][c] = sat8(rintf(v.z * inv[2]));
        vals[3][c] = sat8(rintf(v.w * inv[3]));
    }
#pragma unroll
    for (int q = 0; q < 4; ++q) {
        int2 p;
        p.x = (vals[q][0] & 0xff) | ((vals[q][1] & 0xff) << 8) |
              ((vals[q][2] & 0xff) << 16) | (vals[q][3] << 24);
        p.y = (vals[q][4] & 0xff) | ((vals[q][5] & 0xff) << 8) |
              ((vals[q][6] & 0xff) << 16) | (vals[q][7] << 24);
        *(int2*)&tile[(nf * 4 + q) * 136 + kb] = p;
    }
    __syncthreads();
#pragma unroll
    for (int c = 0; c < 2; ++c) {
        const int idx = c * 256 + t;
        const int row = idx >> 3;          // 0..63
        const int ch = (idx & 7) * 16;     // 0..112
        *(v4i*)&q_rt[(size_t)(n0 + row) * K_DIM + k0 + ch] = *(const v4i*)&tile[row * 136 + ch];
    }
}

// ---------------------------------------------------------------------------
// Kernel 4: int8 MFMA GEMM — R3's known-good 156us version.
// 256x256 tile, BK=128, 4 waves (256 thr), per-wave 128x128 = acc[4][4].
// All-LDS operands, double-buffered, one barrier per phase.
// (R4/R5 established that A-from-global loses: wn-sibling waves duplicate A
// traffic through one TCP port; LDS broadcast is the only cheap fan-out.)
// ---------------------------------------------------------------------------
#define STAGE(dd, kt)                                                          \
    {                                                                          \
        const char* ga = baseA + (kt) * BK;                                    \
        const char* gb = baseB + (kt) * BK;                                    \
        char* la = &lds[(dd) * 65536];                                         \
        char* lb = la + 32768;                                                 \
        _Pragma("unroll")                                                      \
        for (int g = 0; g < 8; ++g) GLOAD_LDS16(ga + goff[g], la + loff[g]);   \
        _Pragma("unroll")                                                      \
        for (int g = 0; g < 8; ++g) GLOAD_LDS16(gb + goff[g], lb + loff[g]);   \
    }

#define PH(dd, h, PRE)                                                         \
    {                                                                          \
        const char* pa = &lds[(dd) * 65536];                                   \
        const char* pb = pa + 32768;                                           \
        v4i af[4][2], bf[4][2];                                                \
        _Pragma("unroll")                                                      \
        for (int s = 0; s < 2; ++s) {                                          \
            _Pragma("unroll")                                                  \
            for (int i = 0; i < 4; ++i)                                        \
                af[i][s] = *(const v4i*)(pa + aoff[i] + cw[2 * (h) + s]);      \
            _Pragma("unroll")                                                  \
            for (int j = 0; j < 4; ++j)                                        \
                bf[j][s] = *(const v4i*)(pb + boff[j] + cw[2 * (h) + s]);      \
        }                                                                      \
        PRE;                                                                   \
        __builtin_amdgcn_s_barrier();                                          \
        _Pragma("unroll")                                                      \
        for (int s = 0; s < 2; ++s)                                            \
            _Pragma("unroll")                                                  \
            for (int i = 0; i < 4; ++i)                                        \
                _Pragma("unroll")                                              \
                for (int j = 0; j < 4; ++j)                                    \
                    acc[i][j] = __builtin_amdgcn_mfma_i32_32x32x32_i8(         \
                        af[i][s], bf[j][s], acc[i][j], 0, 0, 0);               \
    }

__global__ __launch_bounds__(256, 1) void gemm_i8_kernel(const char* __restrict__ qa,
                                                         const char* __restrict__ qb,
                                                         const float* __restrict__ s_l,
                                                         const unsigned* __restrict__ amax_r,
                                                         float* __restrict__ out) {
    __shared__ char lds[131072];
    const int t = threadIdx.x;
    const int lane = t & 63;
    const int ln31 = lane & 31;
    const int lhi = lane >> 5;
    const int wave = t >> 6;          // 0..3
    const int wm = wave >> 1;         // 0..1 (M half)
    const int wn = wave & 1;          // 0..1 (N half)

    // XCD serpentine: XCD x owns bx strip [4x,4x+4) over all by (A-strip 4MB,
    // L2-resident); by-major serpentine for B-panel sharing in time.
    const int orig = blockIdx.x;
    const int x = orig & 7;
    const int idx = orig >> 3;         // 0..63
    const int by = idx >> 2;           // 0..15
    const int bxo = (by & 1) ? (3 - (idx & 3)) : (idx & 3);
    const int bx = x * 4 + bxo;        // 0..31
    const size_t rowA0 = (size_t)bx * 256;
    const size_t rowB0 = (size_t)by * 256;

    v16i acc[4][4];
#pragma unroll
    for (int i = 0; i < 4; ++i)
#pragma unroll
        for (int j = 0; j < 4; ++j) acc[i][j] = (v16i)(0);

    // staging: slot s = g*256+t; r = s>>3 (row 0..255), cs = s&7 (16B chunk
    // in 128B row), source chunk cg = cs ^ (r&7) -> linear LDS dest, swizzled
    // global source (rule #21).
    int goff[8], loff[8];
#pragma unroll
    for (int g = 0; g < 8; ++g) {
        const int s = g * 256 + t;
        const int r = s >> 3;
        const int cg = (s & 7) ^ (r & 7);
        goff[g] = r * K_DIM + cg * 16;
        loff[g] = s * 16;
    }
    const char* baseA = qa + rowA0 * K_DIM;
    const char* baseB = qb + rowB0 * K_DIM;

    // read offsets: fragment row = base + ln31 (rows of 128 B), chunk for
    // kstep ks: c = 2*ks + lhi, lds chunk = c ^ (row&7), row&7 == ln31&7.
    int aoff[4], boff[4], cw[4];
#pragma unroll
    for (int i = 0; i < 4; ++i) aoff[i] = (wm * 128 + i * 32 + ln31) * BK;
#pragma unroll
    for (int j = 0; j < 4; ++j) boff[j] = (wn * 128 + j * 32 + ln31) * BK;
#pragma unroll
    for (int ks = 0; ks < 4; ++ks) cw[ks] = (((2 * ks + lhi) ^ (ln31 & 7)) << 4);

    // Prologue: stage tile 0, drain, barrier.
    STAGE(0, 0);
    asm volatile("s_waitcnt vmcnt(0)" ::: "memory");
    __builtin_amdgcn_s_barrier();

    for (int kt = 0; kt < NT; ++kt) {
        const int d = kt & 1;
        if (kt + 1 < NT) STAGE(d ^ 1, kt + 1);
        PH(d, 0, {});
        PH(d, 1, {
            asm volatile("s_waitcnt vmcnt(0) lgkmcnt(0)" ::: "memory");
            __builtin_amdgcn_sched_barrier(0);
        });
    }

    // Epilogue. 32x32 C/D layout: col=lane&31, row=(reg&3)+8*(reg>>2)+4*(lane>>5)
    float sr[4];
#pragma unroll
    for (int j = 0; j < 4; ++j) {
        const float am = __uint_as_float(amax_r[(int)rowB0 + wn * 128 + j * 32 + ln31]);
        sr[j] = (am > 0.f) ? (am / INT8_BOUND) : 1.f;
    }
#pragma unroll
    for (int i = 0; i < 4; ++i) {
        const int rbase = (int)rowA0 + wm * 128 + i * 32 + 4 * lhi;
        float sl[16];
#pragma unroll
        for (int reg = 0; reg < 16; ++reg)
            sl[reg] = s_l[rbase + (reg & 3) + 8 * (reg >> 2)];
#pragma unroll
        for (int j = 0; j < 4; ++j) {
            const int col = (int)rowB0 + wn * 128 + j * 32 + ln31;
            const v16i a = acc[i][j];
#pragma unroll
            for (int reg = 0; reg < 16; ++reg) {
                const int row = rbase + (reg & 3) + 8 * (reg >> 2);
                out[(size_t)row * N_DIM + col] = (float)a[reg] * sl[reg] * sr[j];
            }
        }
    }
}

// ---------------------------------------------------------------------------
extern "C" void kernel_launch(void* const* d_in, const int* in_sizes, int n_in,
                              void* d_out, int out_size, void* d_ws, size_t ws_size,
                              hipStream_t stream) {
    const float* lhs = (const float*)d_in[0];   // [2,4096,4096] fp32
    const float* rhs = (const float*)d_in[1];   // [4096,4096]  fp32
    float* out = (float*)d_out;                 // [2,4096,4096] fp32

    char* ws = (char*)d_ws;
    char* q_l = ws;                                        // 32 MB
    char* q_rt = ws + (size_t)M_TOT * K_DIM;               // 16 MB
    float* s_l = (float*)(q_rt + (size_t)N_DIM * K_DIM);   // 32 KB
    unsigned* amax_r = (unsigned*)(s_l + M_TOT);           // 16 KB

    hipMemsetAsync(amax_r, 0, N_DIM * sizeof(unsigned), stream);

    // Fused: lhs-quant (8192 blocks) + rhs-amax (1024 blocks) in ONE dispatch
    prep_kernel<<<M_TOT + 1024, 256, 0, stream>>>(lhs, rhs, q_l, s_l, amax_r);
    rhs_quant_kernel<<<dim3(K_DIM / 128, N_DIM / 64), 256, 0, stream>>>(rhs, amax_r, q_rt);
    gemm_i8_kernel<<<dim3((M_TOT / 256) * (N_DIM / 256)), 256, 0, stream>>>(q_l, q_rt, s_l, amax_r, out);
}